// Round 3
// baseline (211.452 us; speedup 1.0000x reference)
//
#include <hip/hip_runtime.h>

// AdditiveAttention: B=4, Q=256, K=1024, DQ=DK=DV=512, H=128
#define B_ 4
#define Q_ 256
#define K_ 1024
#define D_ 512
#define H_ 128
#define DV_ 512
#define SCALE 2.885390081777927f   // 2*log2(e): tanh(x)=1-2/(exp2(S*x)+1)
#define LOG2E 1.4426950408889634f

__device__ __forceinline__ float tanh_e(float x2l) {
    float e = __builtin_amdgcn_exp2f(x2l);
    return 1.0f - 2.0f * __builtin_amdgcn_rcpf(e + 1.0f);
}

// ---------------------------------------------------------------------------
// zero d_out (pv accumulates with atomicAdd over 8 k-splits)
// ---------------------------------------------------------------------------
__global__ __launch_bounds__(512) void zero_kernel(float4* __restrict__ out) {
    out[blockIdx.x * 512 + threadIdx.x] = make_float4(0.f, 0.f, 0.f, 0.f);
}

// ---------------------------------------------------------------------------
// proj: tile 16 rows x 128 h, BK=64, 256 thr (4 waves).
// Wave micro: lane=(lr,lh) 2x32 -> 8 rows x 4 h; waves k-split BK/4=16 kk,
// 3-wave partial reduce through LDS at the end (wave 0 writes results).
// X reads are 2-addr broadcast b128, W reads contiguous-512B b128 -> LDS
// cost ~15 cyc per kk vs 64 cyc FMA: compute-bound.
//   qh_s[row][h]         = S * q[row]·w_q[h]     (blocks 0..63)
//   kh4[b][h>>2][k][h&3] = S * k[b,k]·w_k[h]     (blocks 64..319, mask-skip)
// ---------------------------------------------------------------------------
__global__ __launch_bounds__(256) void proj_kernel(
    const float* __restrict__ qin, const float* __restrict__ kin,
    const float* __restrict__ wq,  const float* __restrict__ wk,
    const int* __restrict__ valid_lens,
    float* __restrict__ qh_s, float* __restrict__ kh4)
{
    __shared__ float Xs[64][20];     // [kk][row] 5.1 KB
    __shared__ float Ws[64][132];    // [kk][h]  33.8 KB
    __shared__ float Rd[3][2048];    // k-split partials 24.6 KB

    const int t   = threadIdx.x;
    const int bid = blockIdx.x;
    const bool isQ = bid < 64;
    const float* X; const float* W; int R0; int b = 0;
    if (isQ) { X = qin; W = wq; R0 = bid * 16; }
    else {
        int kb = bid - 64;
        b  = kb >> 6;
        R0 = (kb & 63) * 16;
        if (R0 >= valid_lens[b]) return;     // block-uniform skip
        X = kin + (size_t)b * K_ * D_;
        W = wk;
    }

    const int wid = t >> 6, lane = t & 63;
    const int lr = lane >> 5, lh = lane & 31;   // rows lr*8.., h lh*4..
    float c[8][4] = {};

    for (int d0 = 0; d0 < D_; d0 += 64) {
        {   // stage X: 16 rows x 64 d = 256 f4, 1/thread
            int row = t >> 4, dd = (t & 15) * 4;
            float4 xv = *(const float4*)&X[(size_t)(R0 + row) * D_ + d0 + dd];
            Xs[dd+0][row] = xv.x; Xs[dd+1][row] = xv.y;
            Xs[dd+2][row] = xv.z; Xs[dd+3][row] = xv.w;
        }
#pragma unroll
        for (int i = 0; i < 8; ++i) {   // stage W: 128 h x 64 d = 2048 f4
            int idx = t + i * 256;
            int h = idx >> 4, dd = (idx & 15) * 4;
            float4 wv4 = *(const float4*)&W[(size_t)h * D_ + d0 + dd];
            Ws[dd+0][h] = wv4.x; Ws[dd+1][h] = wv4.y;
            Ws[dd+2][h] = wv4.z; Ws[dd+3][h] = wv4.w;
        }
        __syncthreads();
        const int k0 = wid * 16;
#pragma unroll
        for (int kk = k0; kk < k0 + 16; ++kk) {
            float xr[8], wr[4];
            *(float4*)&xr[0] = *(const float4*)&Xs[kk][lr*8];
            *(float4*)&xr[4] = *(const float4*)&Xs[kk][lr*8 + 4];
            *(float4*)&wr[0] = *(const float4*)&Ws[kk][lh*4];
#pragma unroll
            for (int i = 0; i < 8; ++i)
#pragma unroll
                for (int j = 0; j < 4; ++j) c[i][j] += xr[i] * wr[j];
        }
        __syncthreads();
    }

    if (wid != 0) {
#pragma unroll
        for (int i = 0; i < 8; ++i)
            *(float4*)&Rd[wid-1][(lr*8 + i)*128 + lh*4] = *(const float4*)&c[i][0];
    }
    __syncthreads();
    if (wid == 0) {
#pragma unroll
        for (int w = 0; w < 3; ++w)
#pragma unroll
            for (int i = 0; i < 8; ++i) {
                float4 r = *(const float4*)&Rd[w][(lr*8 + i)*128 + lh*4];
                c[i][0] += r.x; c[i][1] += r.y; c[i][2] += r.z; c[i][3] += r.w;
            }
        if (isQ) {
#pragma unroll
            for (int i = 0; i < 8; ++i) {
                int row = R0 + lr*8 + i;
                *(float4*)&qh_s[(size_t)row * H_ + lh*4] =
                    make_float4(c[i][0]*SCALE, c[i][1]*SCALE, c[i][2]*SCALE, c[i][3]*SCALE);
            }
        } else {
#pragma unroll
            for (int i = 0; i < 8; ++i) {
                int kk = R0 + lr*8 + i;
                *(float4*)&kh4[(((size_t)(b*32 + lh)) * K_ + kk) * 4] =
                    make_float4(c[i][0]*SCALE, c[i][1]*SCALE, c[i][2]*SCALE, c[i][3]*SCALE);
            }
        }
    }
}

// ---------------------------------------------------------------------------
// scores + masked softmax. 256 blocks = B x Q/4, 512 thr.
// Thread owns k = {t, t+512} for a 4-q tile; each kh float4 feeds 16 tanh.
// Masked k skip the whole tanh loop (exp(-1e6-m)==0 exactly -> equivalent).
// Writes unnormalized exp to p_ws, 1/sum to rs_ws.
// ---------------------------------------------------------------------------
__global__ __launch_bounds__(512) void scores_kernel(
    const float* __restrict__ qh_s, const float4* __restrict__ kh4,
    const float* __restrict__ wvg,  const int* __restrict__ valid_lens,
    float* __restrict__ p_ws, float* __restrict__ rs_ws)
{
    __shared__ float qv[512];
    __shared__ float wvs[128];
    __shared__ float p[4][1024];
    __shared__ float redm[8], reds[8];

    const int t   = threadIdx.x;
    const int bid = blockIdx.x;              // [0,256)
    const int b   = bid >> 6;
    const int q0  = (bid & 63) * 4;

    qv[t] = qh_s[(size_t)(b*Q_ + q0) * H_ + t];
    if (t < 128) wvs[t] = wvg[t];
    __syncthreads();

    const int vl = valid_lens[b];
    const float4* khb = kh4 + (size_t)b * 32 * K_;

    float acc[4][2] = {};
    const bool act0 = t < vl;
    const bool act1 = (t + 512) < vl;
    for (int hq = 0; hq < 32; ++hq) {
        float w4[4], q4[4][4];
        *(float4*)&w4[0] = *(const float4*)&wvs[hq*4];
#pragma unroll
        for (int qi = 0; qi < 4; ++qi)
            *(float4*)&q4[qi][0] = *(const float4*)&qv[qi*128 + hq*4];
        if (act0) {
            float kx[4];
            *(float4*)&kx[0] = khb[(size_t)hq * K_ + t];
#pragma unroll
            for (int hh = 0; hh < 4; ++hh)
#pragma unroll
                for (int qi = 0; qi < 4; ++qi)
                    acc[qi][0] += w4[hh] * tanh_e(q4[qi][hh] + kx[hh]);
        }
        if (act1) {
            float kx[4];
            *(float4*)&kx[0] = khb[(size_t)hq * K_ + t + 512];
#pragma unroll
            for (int hh = 0; hh < 4; ++hh)
#pragma unroll
                for (int qi = 0; qi < 4; ++qi)
                    acc[qi][1] += w4[hh] * tanh_e(q4[qi][hh] + kx[hh]);
        }
    }
#pragma unroll
    for (int qi = 0; qi < 4; ++qi) { p[qi][t] = acc[qi][0]; p[qi][t+512] = acc[qi][1]; }
    __syncthreads();

    // softmax: wave w -> row w>>1, k-half w&1 (2 x 256 float4 passes)
    const int wid = t >> 6, lane = t & 63;
    const int row = wid >> 1, half = wid & 1;
    const int kbase = half * 512;
    float4 s[2];
    float m = -3.0e38f;
#pragma unroll
    for (int i = 0; i < 2; ++i) {
        int kb = kbase + i*256 + lane*4;
        s[i] = *(const float4*)&p[row][kb];
        if (kb + 0 < vl) m = fmaxf(m, s[i].x);
        if (kb + 1 < vl) m = fmaxf(m, s[i].y);
        if (kb + 2 < vl) m = fmaxf(m, s[i].z);
        if (kb + 3 < vl) m = fmaxf(m, s[i].w);
    }
#pragma unroll
    for (int off = 32; off > 0; off >>= 1) m = fmaxf(m, __shfl_xor(m, off));
    if (lane == 0) redm[wid] = m;
    __syncthreads();
    m = fmaxf(redm[row*2], redm[row*2 + 1]);

    float sum = 0.f;
    float4 e[2];
#pragma unroll
    for (int i = 0; i < 2; ++i) {
        int kb = kbase + i*256 + lane*4;
        e[i].x = (kb + 0 < vl) ? __builtin_amdgcn_exp2f((s[i].x - m) * LOG2E) : 0.f;
        e[i].y = (kb + 1 < vl) ? __builtin_amdgcn_exp2f((s[i].y - m) * LOG2E) : 0.f;
        e[i].z = (kb + 2 < vl) ? __builtin_amdgcn_exp2f((s[i].z - m) * LOG2E) : 0.f;
        e[i].w = (kb + 3 < vl) ? __builtin_amdgcn_exp2f((s[i].w - m) * LOG2E) : 0.f;
        sum += e[i].x + e[i].y + e[i].z + e[i].w;
    }
#pragma unroll
    for (int off = 32; off > 0; off >>= 1) sum += __shfl_xor(sum, off);
    if (lane == 0) reds[wid] = sum;
    __syncthreads();
    float tot = reds[row*2] + reds[row*2 + 1];

#pragma unroll
    for (int i = 0; i < 2; ++i)
        *(float4*)&p_ws[(size_t)(b*Q_ + q0 + row) * K_ + kbase + i*256 + lane*4] = e[i];
    if (lane == 0 && half == 0)
        rs_ws[b*Q_ + q0 + row] = __builtin_amdgcn_rcpf(tot);
}

// ---------------------------------------------------------------------------
// pv: out[b,q,dv] += (p/sum)·v. Tile 64q x 128dv x 128k (2 BK=64 chunks),
// grid 512 = [b4][qt4][dvt4][ks8], 128 thr (2 waves, dv-halves).
// Wave micro 8q x 8dv per lane: all inner LDS reads are 8-addr-broadcast
// b128 -> ~1 B/FMA, FMA-bound. k-splits combine via atomicAdd (out zeroed).
// p is exactly 0 for k >= vl, so partial chunks need no masking.
// ---------------------------------------------------------------------------
__global__ __launch_bounds__(128) void pv_kernel(
    const float* __restrict__ p_ws, const float* __restrict__ vin,
    const float* __restrict__ rs_ws, const int* __restrict__ valid_lens,
    float* __restrict__ out)
{
    __shared__ float Ps[64][68];     // [kk][q]  17.4 KB
    __shared__ float Vs[64][132];    // [kk][dv] 33.8 KB

    const int t   = threadIdx.x;
    const int bid = blockIdx.x;
    const int ks  = bid & 7, dvt = (bid >> 3) & 3, qt = (bid >> 5) & 3, b = bid >> 7;
    const int Q0 = qt * 64, DV0 = dvt * 128, Kbase = ks * 128;

    const int vl = valid_lens[b];
    if (Kbase >= vl) return;                        // block-uniform skip
    const int rem = vl - Kbase;
    const int nch = ((rem < 128 ? rem : 128) + 63) >> 6;

    const int wid = t >> 6, lane = t & 63;
    const int lq = lane >> 3, ldv = lane & 7;
    const int dvh = wid * 64;
    float c[8][8] = {};

    for (int ch = 0; ch < nch; ++ch) {
        const int kc = Kbase + ch * 64;
#pragma unroll
        for (int i = 0; i < 8; ++i) {   // stage P: 64q x 64k = 1024 f4
            int idx = t + i * 128;
            int qq = idx >> 4, kd = (idx & 15) * 4;
            float4 pv4 = *(const float4*)&p_ws[(size_t)(b*Q_ + Q0 + qq) * K_ + kc + kd];
            Ps[kd+0][qq] = pv4.x; Ps[kd+1][qq] = pv4.y;
            Ps[kd+2][qq] = pv4.z; Ps[kd+3][qq] = pv4.w;
        }
#pragma unroll
        for (int i = 0; i < 16; ++i) {  // stage V: 64k x 128dv = 2048 f4
            int idx = t + i * 128;
            int kk = idx >> 5, dd = (idx & 31) * 4;
            *(float4*)&Vs[kk][dd] =
                *(const float4*)&vin[(size_t)(b*K_ + kc + kk) * DV_ + DV0 + dd];
        }
        __syncthreads();
#pragma unroll 4
        for (int kk = 0; kk < 64; ++kk) {
            float pr[8], vr[8];
            *(float4*)&pr[0] = *(const float4*)&Ps[kk][lq*8];
            *(float4*)&pr[4] = *(const float4*)&Ps[kk][lq*8 + 4];
            *(float4*)&vr[0] = *(const float4*)&Vs[kk][dvh + ldv*8];
            *(float4*)&vr[4] = *(const float4*)&Vs[kk][dvh + ldv*8 + 4];
#pragma unroll
            for (int i = 0; i < 8; ++i)
#pragma unroll
                for (int j = 0; j < 8; ++j) c[i][j] += pr[i] * vr[j];
        }
        __syncthreads();
    }

#pragma unroll
    for (int i = 0; i < 8; ++i) {
        int q = Q0 + lq*8 + i;
        float rs = rs_ws[b*Q_ + q];
        float* base = out + (size_t)(b*Q_ + q) * DV_ + DV0 + dvh + ldv*8;
#pragma unroll
        for (int j = 0; j < 8; ++j) atomicAdd(base + j, c[i][j] * rs);
    }
}

extern "C" void kernel_launch(void* const* d_in, const int* in_sizes, int n_in,
                              void* d_out, int out_size, void* d_ws, size_t ws_size,
                              hipStream_t stream)
{
    const float* q  = (const float*)d_in[0];
    const float* k  = (const float*)d_in[1];
    const float* v  = (const float*)d_in[2];
    const int*   vl = (const int*)d_in[3];
    const float* wq = (const float*)d_in[4];
    const float* wk = (const float*)d_in[5];
    const float* wv = (const float*)d_in[6];
    float* out = (float*)d_out;

    float* qh_s = (float*)d_ws;                       //  131072 floats
    float* kh4  = qh_s + (size_t)B_*Q_*H_;            //  524288 floats
    float* p_ws = kh4  + (size_t)B_*H_*K_;            // 1048576 floats
    float* rs_ws= p_ws + (size_t)B_*Q_*K_;            //    1024 floats

    zero_kernel  <<<dim3(256), dim3(512), 0, stream>>>((float4*)out);
    proj_kernel  <<<dim3(320), dim3(256), 0, stream>>>(q, k, wq, wk, vl, qh_s, kh4);
    scores_kernel<<<dim3(256), dim3(512), 0, stream>>>(qh_s, (const float4*)kh4, wv, vl, p_ws, rs_ws);
    pv_kernel    <<<dim3(512), dim3(128), 0, stream>>>(p_ws, v, rs_ws, vl, out);
}

// Round 4
// 168.491 us; speedup vs baseline: 1.2550x; 1.2550x over previous
//
#include <hip/hip_runtime.h>

// AdditiveAttention: B=4, Q=256, K=1024, DQ=DK=DV=512, H=128
#define B_ 4
#define Q_ 256
#define K_ 1024
#define D_ 512
#define H_ 128
#define DV_ 512
#define SCALE 2.885390081777927f   // 2*log2(e): tanh(x)=1-2/(exp2(S*x)+1)
#define LOG2E 1.4426950408889634f

// rcp(exp2(x)+1); Sum_h w*tanh = wsum - 2*Sum_h w*sigl
__device__ __forceinline__ float sigl(float x2l) {
    return __builtin_amdgcn_rcpf(__builtin_amdgcn_exp2f(x2l) + 1.0f);
}

// ---------------------------------------------------------------------------
// proj (unchanged from round 3): tile 16 rows x 128 h, BK=64, 256 thr.
//   qh_s[row][h]         = S * q[row]·w_q[h]     (blocks 0..63)
//   kh4[b][h>>2][k][h&3] = S * k[b,k]·w_k[h]     (blocks 64..319, mask-skip)
// ---------------------------------------------------------------------------
__global__ __launch_bounds__(256) void proj_kernel(
    const float* __restrict__ qin, const float* __restrict__ kin,
    const float* __restrict__ wq,  const float* __restrict__ wk,
    const int* __restrict__ valid_lens,
    float* __restrict__ qh_s, float* __restrict__ kh4)
{
    __shared__ float Xs[64][20];
    __shared__ float Ws[64][132];
    __shared__ float Rd[3][2048];

    const int t   = threadIdx.x;
    const int bid = blockIdx.x;
    const bool isQ = bid < 64;
    const float* X; const float* W; int R0; int b = 0;
    if (isQ) { X = qin; W = wq; R0 = bid * 16; }
    else {
        int kb = bid - 64;
        b  = kb >> 6;
        R0 = (kb & 63) * 16;
        if (R0 >= valid_lens[b]) return;
        X = kin + (size_t)b * K_ * D_;
        W = wk;
    }

    const int wid = t >> 6, lane = t & 63;
    const int lr = lane >> 5, lh = lane & 31;
    float c[8][4] = {};

    for (int d0 = 0; d0 < D_; d0 += 64) {
        {
            int row = t >> 4, dd = (t & 15) * 4;
            float4 xv = *(const float4*)&X[(size_t)(R0 + row) * D_ + d0 + dd];
            Xs[dd+0][row] = xv.x; Xs[dd+1][row] = xv.y;
            Xs[dd+2][row] = xv.z; Xs[dd+3][row] = xv.w;
        }
#pragma unroll
        for (int i = 0; i < 8; ++i) {
            int idx = t + i * 256;
            int h = idx >> 4, dd = (idx & 15) * 4;
            float4 wv4 = *(const float4*)&W[(size_t)h * D_ + d0 + dd];
            Ws[dd+0][h] = wv4.x; Ws[dd+1][h] = wv4.y;
            Ws[dd+2][h] = wv4.z; Ws[dd+3][h] = wv4.w;
        }
        __syncthreads();
        const int k0 = wid * 16;
#pragma unroll
        for (int kk = k0; kk < k0 + 16; ++kk) {
            float xr[8], wr[4];
            *(float4*)&xr[0] = *(const float4*)&Xs[kk][lr*8];
            *(float4*)&xr[4] = *(const float4*)&Xs[kk][lr*8 + 4];
            *(float4*)&wr[0] = *(const float4*)&Ws[kk][lh*4];
#pragma unroll
            for (int i = 0; i < 8; ++i)
#pragma unroll
                for (int j = 0; j < 4; ++j) c[i][j] += xr[i] * wr[j];
        }
        __syncthreads();
    }

    if (wid != 0) {
#pragma unroll
        for (int i = 0; i < 8; ++i)
            *(float4*)&Rd[wid-1][(lr*8 + i)*128 + lh*4] = *(const float4*)&c[i][0];
    }
    __syncthreads();
    if (wid == 0) {
#pragma unroll
        for (int w = 0; w < 3; ++w)
#pragma unroll
            for (int i = 0; i < 8; ++i) {
                float4 r = *(const float4*)&Rd[w][(lr*8 + i)*128 + lh*4];
                c[i][0] += r.x; c[i][1] += r.y; c[i][2] += r.z; c[i][3] += r.w;
            }
        if (isQ) {
#pragma unroll
            for (int i = 0; i < 8; ++i) {
                int row = R0 + lr*8 + i;
                *(float4*)&qh_s[(size_t)row * H_ + lh*4] =
                    make_float4(c[i][0]*SCALE, c[i][1]*SCALE, c[i][2]*SCALE, c[i][3]*SCALE);
            }
        } else {
#pragma unroll
            for (int i = 0; i < 8; ++i) {
                int kk = R0 + lr*8 + i;
                *(float4*)&kh4[(((size_t)(b*32 + lh)) * K_ + kk) * 4] =
                    make_float4(c[i][0]*SCALE, c[i][1]*SCALE, c[i][2]*SCALE, c[i][3]*SCALE);
            }
        }
    }
}

// ---------------------------------------------------------------------------
// Fused scores + masked softmax + PV. 256 blocks = B x Q/4, 512 thr (8 waves).
// Phase B: thread owns k={t,t+512}; per kh float4 -> 16 sigl terms;
//          masked k skip entirely. score = wsum - 2*acc.
// Phase C: wave w -> (row=w>>1, k-half=w&1); e written back into LDS p.
// Phase D: wave w -> (qrow=w>>1, dv-half=w&1); p broadcast from LDS (uniform
//          b128, conflict-free), v streamed from global (L2-resident,
//          coalesced f4); no barriers, no atomics; wave stores its out slice.
// ---------------------------------------------------------------------------
__global__ __launch_bounds__(512) void attn_kernel(
    const float* __restrict__ qh_s, const float4* __restrict__ kh4,
    const float* __restrict__ wvg,  const int* __restrict__ valid_lens,
    const float* __restrict__ vin,  float* __restrict__ out)
{
    __shared__ float qv[512];
    __shared__ float wvs[128];
    __shared__ float p[4][1024];
    __shared__ float redm[8], reds[8];
    __shared__ float rstat[4];

    const int t   = threadIdx.x;
    const int bid = blockIdx.x;              // [0,256)
    const int b   = bid >> 6;
    const int q0  = (bid & 63) * 4;

    qv[t] = qh_s[(size_t)(b*Q_ + q0) * H_ + t];
    if (t < 128) wvs[t] = wvg[t];
    __syncthreads();

    const int vl = valid_lens[b];
    const float4* khb = kh4 + (size_t)b * 32 * K_;

    float wsum = 0.f;
#pragma unroll
    for (int hq = 0; hq < 32; ++hq) {
        float4 w4 = *(const float4*)&wvs[hq*4];
        wsum += w4.x + w4.y + w4.z + w4.w;
    }

    // ---- Phase B: scores ----
    float acc[4][2] = {};
    const bool act0 = t < vl;
    const bool act1 = (t + 512) < vl;
    for (int hq = 0; hq < 32; ++hq) {
        float w4[4], q4[4][4];
        *(float4*)&w4[0] = *(const float4*)&wvs[hq*4];
#pragma unroll
        for (int qi = 0; qi < 4; ++qi)
            *(float4*)&q4[qi][0] = *(const float4*)&qv[qi*128 + hq*4];
        if (act0) {
            float kx[4];
            *(float4*)&kx[0] = khb[(size_t)hq * K_ + t];
#pragma unroll
            for (int hh = 0; hh < 4; ++hh)
#pragma unroll
                for (int qi = 0; qi < 4; ++qi)
                    acc[qi][0] += w4[hh] * sigl(q4[qi][hh] + kx[hh]);
        }
        if (act1) {
            float kx[4];
            *(float4*)&kx[0] = khb[(size_t)hq * K_ + t + 512];
#pragma unroll
            for (int hh = 0; hh < 4; ++hh)
#pragma unroll
                for (int qi = 0; qi < 4; ++qi)
                    acc[qi][1] += w4[hh] * sigl(q4[qi][hh] + kx[hh]);
        }
    }
#pragma unroll
    for (int qi = 0; qi < 4; ++qi) {
        p[qi][t]       = wsum - 2.f * acc[qi][0];
        p[qi][t + 512] = wsum - 2.f * acc[qi][1];
    }
    __syncthreads();

    // ---- Phase C: masked softmax ----
    const int wid = t >> 6, lane = t & 63;
    const int row = wid >> 1, half = wid & 1;
    const int kbase = half * 512;
    float4 s[2];
    float m = -3.0e38f;
#pragma unroll
    for (int i = 0; i < 2; ++i) {
        int kb = kbase + i*256 + lane*4;
        s[i] = *(const float4*)&p[row][kb];
        if (kb + 0 < vl) m = fmaxf(m, s[i].x);
        if (kb + 1 < vl) m = fmaxf(m, s[i].y);
        if (kb + 2 < vl) m = fmaxf(m, s[i].z);
        if (kb + 3 < vl) m = fmaxf(m, s[i].w);
    }
#pragma unroll
    for (int off = 32; off > 0; off >>= 1) m = fmaxf(m, __shfl_xor(m, off));
    if (lane == 0) redm[wid] = m;
    __syncthreads();
    m = fmaxf(redm[row*2], redm[row*2 + 1]);

    float sum = 0.f;
    float4 e[2];
#pragma unroll
    for (int i = 0; i < 2; ++i) {
        int kb = kbase + i*256 + lane*4;
        e[i].x = (kb + 0 < vl) ? __builtin_amdgcn_exp2f((s[i].x - m) * LOG2E) : 0.f;
        e[i].y = (kb + 1 < vl) ? __builtin_amdgcn_exp2f((s[i].y - m) * LOG2E) : 0.f;
        e[i].z = (kb + 2 < vl) ? __builtin_amdgcn_exp2f((s[i].z - m) * LOG2E) : 0.f;
        e[i].w = (kb + 3 < vl) ? __builtin_amdgcn_exp2f((s[i].w - m) * LOG2E) : 0.f;
        sum += e[i].x + e[i].y + e[i].z + e[i].w;
        *(float4*)&p[row][kb] = e[i];
    }
#pragma unroll
    for (int off = 32; off > 0; off >>= 1) sum += __shfl_xor(sum, off);
    if (lane == 0) reds[wid] = sum;
    __syncthreads();
    if (lane == 0 && half == 0)
        rstat[row] = __builtin_amdgcn_rcpf(reds[row*2] + reds[row*2 + 1]);
    __syncthreads();

    // ---- Phase D: PV ----
    const int qrow = wid >> 1;
    const int col  = (wid & 1) * 64 + lane;          // float4 column 0..127
    const float4* vb = (const float4*)vin + (size_t)b * K_ * (DV_/4);
    const float* prow = p[qrow];
    float4 o = make_float4(0.f, 0.f, 0.f, 0.f);

    int k = 0;
    for (; k + 8 <= vl; k += 8) {
        float4 pa = *(const float4*)&prow[k];
        float4 pb2 = *(const float4*)&prow[k+4];
        float4 v0 = vb[(size_t)(k+0)*128 + col];
        float4 v1 = vb[(size_t)(k+1)*128 + col];
        float4 v2 = vb[(size_t)(k+2)*128 + col];
        float4 v3 = vb[(size_t)(k+3)*128 + col];
        float4 v4 = vb[(size_t)(k+4)*128 + col];
        float4 v5 = vb[(size_t)(k+5)*128 + col];
        float4 v6 = vb[(size_t)(k+6)*128 + col];
        float4 v7 = vb[(size_t)(k+7)*128 + col];
        o.x += pa.x*v0.x + pa.y*v1.x + pa.z*v2.x + pa.w*v3.x
             + pb2.x*v4.x + pb2.y*v5.x + pb2.z*v6.x + pb2.w*v7.x;
        o.y += pa.x*v0.y + pa.y*v1.y + pa.z*v2.y + pa.w*v3.y
             + pb2.x*v4.y + pb2.y*v5.y + pb2.z*v6.y + pb2.w*v7.y;
        o.z += pa.x*v0.z + pa.y*v1.z + pa.z*v2.z + pa.w*v3.z
             + pb2.x*v4.z + pb2.y*v5.z + pb2.z*v6.z + pb2.w*v7.z;
        o.w += pa.x*v0.w + pa.y*v1.w + pa.z*v2.w + pa.w*v3.w
             + pb2.x*v4.w + pb2.y*v5.w + pb2.z*v6.w + pb2.w*v7.w;
    }
    for (; k < vl; ++k) {
        float pk = prow[k];
        float4 v0 = vb[(size_t)k*128 + col];
        o.x += pk*v0.x; o.y += pk*v0.y; o.z += pk*v0.z; o.w += pk*v0.w;
    }

    float rs = rstat[qrow];
    *(float4*)&out[(size_t)(b*Q_ + q0 + qrow) * DV_ + col*4] =
        make_float4(o.x*rs, o.y*rs, o.z*rs, o.w*rs);
}

extern "C" void kernel_launch(void* const* d_in, const int* in_sizes, int n_in,
                              void* d_out, int out_size, void* d_ws, size_t ws_size,
                              hipStream_t stream)
{
    const float* q  = (const float*)d_in[0];
    const float* k  = (const float*)d_in[1];
    const float* v  = (const float*)d_in[2];
    const int*   vl = (const int*)d_in[3];
    const float* wq = (const float*)d_in[4];
    const float* wk = (const float*)d_in[5];
    const float* wv = (const float*)d_in[6];
    float* out = (float*)d_out;

    float* qh_s = (float*)d_ws;                       // 131072 floats
    float* kh4  = qh_s + (size_t)B_*Q_*H_;            // 524288 floats

    proj_kernel<<<dim3(320), dim3(256), 0, stream>>>(q, k, wq, wk, vl, qh_s, kh4);
    attn_kernel<<<dim3(256), dim3(512), 0, stream>>>(qh_s, (const float4*)kh4, wv, vl, v, out);
}

// Round 5
// 167.914 us; speedup vs baseline: 1.2593x; 1.0034x over previous
//
#include <hip/hip_runtime.h>

// AdditiveAttention: B=4, Q=256, K=1024, DQ=DK=DV=512, H=128
#define B_ 4
#define Q_ 256
#define K_ 1024
#define D_ 512
#define H_ 128
#define DV_ 512
#define SCALE 2.885390081777927f    // 2*log2(e): tanh(x)=1-2/(exp2(S*x)+1)
#define LOG2E 1.4426950408889634f
#define N2LOG2E (-2.0f * 1.4426950408889634f)

// rcp(exp2(x)+1); Sum_h w*tanh = wsum - 2*Sum_h w*sigl
__device__ __forceinline__ float sigl(float x) {
    return __builtin_amdgcn_rcpf(__builtin_amdgcn_exp2f(x) + 1.0f);
}

// ---------------------------------------------------------------------------
// zero s_acc (1024 f) + o_acc (524288 f), contiguous: 131328 float4
// ---------------------------------------------------------------------------
__global__ __launch_bounds__(256) void zero_kernel(float4* __restrict__ p) {
    p[blockIdx.x * 256 + threadIdx.x] = make_float4(0.f, 0.f, 0.f, 0.f);
}

// ---------------------------------------------------------------------------
// proj (unchanged from round 3/4): tile 16 rows x 128 h, BK=64, 256 thr.
//   qh_s[row][h]         = S * q[row]·w_q[h]     (blocks 0..63)
//   kh4[b][h>>2][k][h&3] = S * k[b,k]·w_k[h]     (blocks 64..319, mask-skip)
// ---------------------------------------------------------------------------
__global__ __launch_bounds__(256) void proj_kernel(
    const float* __restrict__ qin, const float* __restrict__ kin,
    const float* __restrict__ wq,  const float* __restrict__ wk,
    const int* __restrict__ valid_lens,
    float* __restrict__ qh_s, float* __restrict__ kh4)
{
    __shared__ float Xs[64][20];
    __shared__ float Ws[64][132];
    __shared__ float Rd[3][2048];

    const int t   = threadIdx.x;
    const int bid = blockIdx.x;
    const bool isQ = bid < 64;
    const float* X; const float* W; int R0; int b = 0;
    if (isQ) { X = qin; W = wq; R0 = bid * 16; }
    else {
        int kb = bid - 64;
        b  = kb >> 6;
        R0 = (kb & 63) * 16;
        if (R0 >= valid_lens[b]) return;
        X = kin + (size_t)b * K_ * D_;
        W = wk;
    }

    const int wid = t >> 6, lane = t & 63;
    const int lr = lane >> 5, lh = lane & 31;
    float c[8][4] = {};

    for (int d0 = 0; d0 < D_; d0 += 64) {
        {
            int row = t >> 4, dd = (t & 15) * 4;
            float4 xv = *(const float4*)&X[(size_t)(R0 + row) * D_ + d0 + dd];
            Xs[dd+0][row] = xv.x; Xs[dd+1][row] = xv.y;
            Xs[dd+2][row] = xv.z; Xs[dd+3][row] = xv.w;
        }
#pragma unroll
        for (int i = 0; i < 8; ++i) {
            int idx = t + i * 256;
            int h = idx >> 4, dd = (idx & 15) * 4;
            float4 wv4 = *(const float4*)&W[(size_t)h * D_ + d0 + dd];
            Ws[dd+0][h] = wv4.x; Ws[dd+1][h] = wv4.y;
            Ws[dd+2][h] = wv4.z; Ws[dd+3][h] = wv4.w;
        }
        __syncthreads();
        const int k0 = wid * 16;
#pragma unroll
        for (int kk = k0; kk < k0 + 16; ++kk) {
            float xr[8], wr[4];
            *(float4*)&xr[0] = *(const float4*)&Xs[kk][lr*8];
            *(float4*)&xr[4] = *(const float4*)&Xs[kk][lr*8 + 4];
            *(float4*)&wr[0] = *(const float4*)&Ws[kk][lh*4];
#pragma unroll
            for (int i = 0; i < 8; ++i)
#pragma unroll
                for (int j = 0; j < 4; ++j) c[i][j] += xr[i] * wr[j];
        }
        __syncthreads();
    }

    if (wid != 0) {
#pragma unroll
        for (int i = 0; i < 8; ++i)
            *(float4*)&Rd[wid-1][(lr*8 + i)*128 + lh*4] = *(const float4*)&c[i][0];
    }
    __syncthreads();
    if (wid == 0) {
#pragma unroll
        for (int w = 0; w < 3; ++w)
#pragma unroll
            for (int i = 0; i < 8; ++i) {
                float4 r = *(const float4*)&Rd[w][(lr*8 + i)*128 + lh*4];
                c[i][0] += r.x; c[i][1] += r.y; c[i][2] += r.z; c[i][3] += r.w;
            }
        if (isQ) {
#pragma unroll
            for (int i = 0; i < 8; ++i) {
                int row = R0 + lr*8 + i;
                *(float4*)&qh_s[(size_t)row * H_ + lh*4] =
                    make_float4(c[i][0]*SCALE, c[i][1]*SCALE, c[i][2]*SCALE, c[i][3]*SCALE);
            }
        } else {
#pragma unroll
            for (int i = 0; i < 8; ++i) {
                int kk = R0 + lr*8 + i;
                *(float4*)&kh4[(((size_t)(b*32 + lh)) * K_ + kk) * 4] =
                    make_float4(c[i][0]*SCALE, c[i][1]*SCALE, c[i][2]*SCALE, c[i][3]*SCALE);
            }
        }
    }
}

// ---------------------------------------------------------------------------
// attn_part: scores + exp + partial-PV for one (b, 4-q tile, K-half).
// Grid 512 = [qt:6][b:2][ks:1], 256 thr (4 waves). Blocks past valid_len
// exit immediately. No softmax max-pass: |score| <= Sum|w_v| ~ 5, exp safe;
// softmax is shift-invariant so result is identical.
// Phase B: thread owns k-cols {t, t+256} of its half; 8 sigl per kh float4.
// Phase S: e = exp2(C - 2*log2e*acc); partial row-sums -> s_acc (atomic).
// Phase D: col = t&127 (f4), k in contiguous half-of-half; p broadcast from
//          LDS b128, v streamed from global (L2); halves combined in LDS,
//          then store (vl<=512: single writer) or atomicAdd into o_acc.
// ---------------------------------------------------------------------------
__global__ __launch_bounds__(256) void attn_part(
    const float* __restrict__ qh_s, const float4* __restrict__ kh4,
    const float* __restrict__ wvg,  const int* __restrict__ valid_lens,
    const float* __restrict__ vin,
    float* __restrict__ s_acc, float* __restrict__ o_acc)
{
    __shared__ float qv[512];
    __shared__ float wvs[128];
    __shared__ float p[4][512];
    __shared__ float redw[4][4];

    const int t   = threadIdx.x;
    const int bid = blockIdx.x;
    const int ks  = bid & 1, b = (bid >> 1) & 3, qt = bid >> 3;
    const int q0  = qt * 4;
    const int vl  = valid_lens[b];
    const int kbase = ks * 512;
    if (kbase >= vl) return;
    const int klen = min(512, vl - kbase);
    const bool solo = (vl <= 512);            // this k-half is the only writer

    qv[t]       = qh_s[(size_t)(b*Q_ + q0) * H_ + t];
    qv[t + 256] = qh_s[(size_t)(b*Q_ + q0) * H_ + t + 256];
    if (t < 128) wvs[t] = wvg[t];
    __syncthreads();

    float wsum = 0.f;
#pragma unroll
    for (int i = 0; i < 32; ++i) {
        float4 w = *(const float4*)&wvs[i*4];
        wsum += w.x + w.y + w.z + w.w;
    }
    const float C = wsum * LOG2E;

    // ---- Phase B: scores ----
    const float4* khb = kh4 + (size_t)b * 32 * K_;
    const bool act0 = t < klen;
    const bool act1 = (t + 256) < klen;
    const int k0g = kbase + t, k1g = kbase + t + 256;
    float acc[4][2] = {};
    for (int hq = 0; hq < 32; ++hq) {
        float w4[4], q4[4][4];
        *(float4*)&w4[0] = *(const float4*)&wvs[hq*4];
#pragma unroll
        for (int qi = 0; qi < 4; ++qi)
            *(float4*)&q4[qi][0] = *(const float4*)&qv[qi*128 + hq*4];
        if (act0) {
            float kx[4];
            *(float4*)&kx[0] = khb[(size_t)hq * K_ + k0g];
#pragma unroll
            for (int hh = 0; hh < 4; ++hh)
#pragma unroll
                for (int qi = 0; qi < 4; ++qi)
                    acc[qi][0] += w4[hh] * sigl(q4[qi][hh] + kx[hh]);
        }
        if (act1) {
            float kx[4];
            *(float4*)&kx[0] = khb[(size_t)hq * K_ + k1g];
#pragma unroll
            for (int hh = 0; hh < 4; ++hh)
#pragma unroll
                for (int qi = 0; qi < 4; ++qi)
                    acc[qi][1] += w4[hh] * sigl(q4[qi][hh] + kx[hh]);
        }
    }

    // ---- Phase S: exp + partial sums ----
    float psum[4];
#pragma unroll
    for (int qi = 0; qi < 4; ++qi) {
        float e0 = act0 ? __builtin_amdgcn_exp2f(fmaf(acc[qi][0], N2LOG2E, C)) : 0.f;
        float e1 = act1 ? __builtin_amdgcn_exp2f(fmaf(acc[qi][1], N2LOG2E, C)) : 0.f;
        p[qi][t] = e0;
        p[qi][t + 256] = e1;
        psum[qi] = e0 + e1;
    }
#pragma unroll
    for (int off = 32; off > 0; off >>= 1)
#pragma unroll
        for (int qi = 0; qi < 4; ++qi) psum[qi] += __shfl_xor(psum[qi], off);
    const int wid = t >> 6, lane = t & 63;
    if (lane == 0) {
#pragma unroll
        for (int qi = 0; qi < 4; ++qi) redw[wid][qi] = psum[qi];
    }
    __syncthreads();                          // p + redw ready
    if (t < 4) {
        float s = redw[0][t] + redw[1][t] + redw[2][t] + redw[3][t];
        if (solo) s_acc[b*Q_ + q0 + t] = s;
        else      atomicAdd(&s_acc[b*Q_ + q0 + t], s);
    }

    // ---- Phase D: partial PV ----
    const int col  = t & 127;                 // float4 column of DV/4
    const int half = t >> 7;
    const int hlen = (klen + 1) >> 1;
    const int kb2  = half * hlen;
    const int ke2  = min(klen, kb2 + hlen);
    const float4* vb = (const float4*)vin + (size_t)b * K_ * 128 + (size_t)kbase * 128;

    float4 o0 = make_float4(0,0,0,0), o1 = o0, o2 = o0, o3 = o0;
    int k = kb2;
#define PVACC(oq, pq) \
    oq.x += pq.x*v0.x + pq.y*v1.x + pq.z*v2.x + pq.w*v3.x; \
    oq.y += pq.x*v0.y + pq.y*v1.y + pq.z*v2.y + pq.w*v3.y; \
    oq.z += pq.x*v0.z + pq.y*v1.z + pq.z*v2.z + pq.w*v3.z; \
    oq.w += pq.x*v0.w + pq.y*v1.w + pq.z*v2.w + pq.w*v3.w;
    for (; k + 4 <= ke2; k += 4) {
        float4 p0 = *(const float4*)&p[0][k];
        float4 p1 = *(const float4*)&p[1][k];
        float4 p2 = *(const float4*)&p[2][k];
        float4 p3 = *(const float4*)&p[3][k];
        float4 v0 = vb[(size_t)(k+0)*128 + col];
        float4 v1 = vb[(size_t)(k+1)*128 + col];
        float4 v2 = vb[(size_t)(k+2)*128 + col];
        float4 v3 = vb[(size_t)(k+3)*128 + col];
        PVACC(o0, p0) PVACC(o1, p1) PVACC(o2, p2) PVACC(o3, p3)
    }
#undef PVACC
    for (; k < ke2; ++k) {
        float4 v0 = vb[(size_t)k*128 + col];
        float pk;
        pk = p[0][k]; o0.x += pk*v0.x; o0.y += pk*v0.y; o0.z += pk*v0.z; o0.w += pk*v0.w;
        pk = p[1][k]; o1.x += pk*v0.x; o1.y += pk*v0.y; o1.z += pk*v0.z; o1.w += pk*v0.w;
        pk = p[2][k]; o2.x += pk*v0.x; o2.y += pk*v0.y; o2.z += pk*v0.z; o2.w += pk*v0.w;
        pk = p[3][k]; o3.x += pk*v0.x; o3.y += pk*v0.y; o3.z += pk*v0.z; o3.w += pk*v0.w;
    }

    // combine the two k-sub-halves through LDS (reuse p as float4[4][128])
    __syncthreads();                          // everyone done reading p
    if (half == 1) {
        ((float4*)&p[0][0])[col] = o0;
        ((float4*)&p[1][0])[col] = o1;
        ((float4*)&p[2][0])[col] = o2;
        ((float4*)&p[3][0])[col] = o3;
    }
    __syncthreads();
    if (half == 0) {
        float4 r;
        r = ((float4*)&p[0][0])[col]; o0.x += r.x; o0.y += r.y; o0.z += r.z; o0.w += r.w;
        r = ((float4*)&p[1][0])[col]; o1.x += r.x; o1.y += r.y; o1.z += r.z; o1.w += r.w;
        r = ((float4*)&p[2][0])[col]; o2.x += r.x; o2.y += r.y; o2.z += r.z; o2.w += r.w;
        r = ((float4*)&p[3][0])[col]; o3.x += r.x; o3.y += r.y; o3.z += r.z; o3.w += r.w;
        float4 os[4] = {o0, o1, o2, o3};
#pragma unroll
        for (int qi = 0; qi < 4; ++qi) {
            float* base = &o_acc[((size_t)(b*Q_ + q0 + qi) * 128 + col) * 4];
            if (solo) {
                *(float4*)base = os[qi];
            } else {
                atomicAdd(base+0, os[qi].x);
                atomicAdd(base+1, os[qi].y);
                atomicAdd(base+2, os[qi].z);
                atomicAdd(base+3, os[qi].w);
            }
        }
    }
}

// ---------------------------------------------------------------------------
// finalize: out = o_acc * rcp(s_acc[row]).  131072 float4.
// ---------------------------------------------------------------------------
__global__ __launch_bounds__(256) void finalize_kernel(
    const float4* __restrict__ o_acc, const float* __restrict__ s_acc,
    float4* __restrict__ out)
{
    int gid = blockIdx.x * 256 + threadIdx.x;     // [0, 131072)
    int row = gid >> 7;
    float rs = __builtin_amdgcn_rcpf(s_acc[row]);
    float4 o = o_acc[gid];
    out[gid] = make_float4(o.x*rs, o.y*rs, o.z*rs, o.w*rs);
}

extern "C" void kernel_launch(void* const* d_in, const int* in_sizes, int n_in,
                              void* d_out, int out_size, void* d_ws, size_t ws_size,
                              hipStream_t stream)
{
    const float* q  = (const float*)d_in[0];
    const float* k  = (const float*)d_in[1];
    const float* v  = (const float*)d_in[2];
    const int*   vl = (const int*)d_in[3];
    const float* wq = (const float*)d_in[4];
    const float* wk = (const float*)d_in[5];
    const float* wv = (const float*)d_in[6];
    float* out = (float*)d_out;

    float* qh_s = (float*)d_ws;                       // 131072 f
    float* kh4  = qh_s + (size_t)B_*Q_*H_;            // 524288 f
    float* s_acc= kh4  + (size_t)B_*H_*K_;            //   1024 f
    float* o_acc= s_acc + B_*Q_;                      // 524288 f  (contiguous w/ s_acc)

    zero_kernel    <<<dim3(513), dim3(256), 0, stream>>>((float4*)s_acc);
    proj_kernel    <<<dim3(320), dim3(256), 0, stream>>>(q, k, wq, wk, vl, qh_s, kh4);
    attn_part      <<<dim3(512), dim3(256), 0, stream>>>(qh_s, (const float4*)kh4, wv, vl, v, s_acc, o_acc);
    finalize_kernel<<<dim3(512), dim3(256), 0, stream>>>((const float4*)o_acc, s_acc, (float4*)out);
}

// Round 6
// 152.589 us; speedup vs baseline: 1.3858x; 1.1004x over previous
//
#include <hip/hip_runtime.h>

// AdditiveAttention: B=4, Q=256, K=1024, DQ=DK=DV=512, H=128
#define B_ 4
#define Q_ 256
#define K_ 1024
#define D_ 512
#define H_ 128
#define DV_ 512
#define SCALE 2.885390081777927f    // 2*log2(e): tanh(x)=1-2/(exp2(S*x)+1)
#define LOG2E 1.4426950408889634f
#define N2LOG2E (-2.0f * 1.4426950408889634f)

// rcp(exp2(x)+1); Sum_h w*tanh = wsum - 2*Sum_h w*sigl
__device__ __forceinline__ float sigl(float x) {
    return __builtin_amdgcn_rcpf(__builtin_amdgcn_exp2f(x) + 1.0f);
}

// ---------------------------------------------------------------------------
// transpose_w: WT[d][h] = W[h][d] for wq and wk. 16 blocks = [m:2][dt:8].
// ---------------------------------------------------------------------------
__global__ __launch_bounds__(256) void transpose_w(
    const float* __restrict__ wq, const float* __restrict__ wk,
    float* __restrict__ wt_q, float* __restrict__ wt_k)
{
    __shared__ float Ts[64][133];
    const int t = threadIdx.x, bid = blockIdx.x;
    const int m = bid >> 3, d0 = (bid & 7) * 64;
    const float* W  = m ? wk : wq;
    float*       WT = m ? wt_k : wt_q;
#pragma unroll
    for (int i = 0; i < 8; ++i) {
        int idx = i * 256 + t;
        int h = idx >> 4, dq = idx & 15;
        float4 v = *(const float4*)&W[(size_t)h * D_ + d0 + dq*4];
        Ts[dq*4+0][h] = v.x; Ts[dq*4+1][h] = v.y;
        Ts[dq*4+2][h] = v.z; Ts[dq*4+3][h] = v.w;
    }
    __syncthreads();
#pragma unroll
    for (int i = 0; i < 8; ++i) {
        int idx = i * 256 + t;
        int d = idx >> 5, h4 = idx & 31;
        *(float4*)&WT[(size_t)(d0 + d) * H_ + h4*4] = *(const float4*)&Ts[d][h4*4];
    }
}

// ---------------------------------------------------------------------------
// proj2: 16 rows x 128 h per block, 256 thr. W read coalesced from WT (L2,
// 256 KB reused by all blocks), X-tile broadcast from LDS. FMA-bound.
//   qh_s[row][h]         (blocks 0..63)
//   kh4[b][h>>2][k][h&3] (blocks 64..319, tiles past valid_len skipped)
// ---------------------------------------------------------------------------
__global__ __launch_bounds__(256) void proj2_kernel(
    const float* __restrict__ qin, const float* __restrict__ kin,
    const float* __restrict__ wt_q, const float* __restrict__ wt_k,
    const int* __restrict__ valid_lens,
    float* __restrict__ qh_s, float4* __restrict__ kh4)
{
    __shared__ float Xs[16][512];    // 32 KB

    const int t = threadIdx.x, bid = blockIdx.x;
    const bool isQ = bid < 64;
    const float* X; const float* WT; int R0; int b = 0;
    if (isQ) { X = qin; WT = wt_q; R0 = bid * 16; }
    else {
        int kb = bid - 64;
        b  = kb >> 6;
        R0 = (kb & 63) * 16;
        if (R0 >= valid_lens[b]) return;
        X = kin + (size_t)b * K_ * D_;
        WT = wt_k;
    }

#pragma unroll
    for (int i = 0; i < 8; ++i) {       // stage 16x512 X tile
        int idx = i * 256 + t;
        int row = idx >> 7, d4 = idx & 127;
        *(float4*)&Xs[row][d4*4] = *(const float4*)&X[(size_t)(R0 + row) * D_ + d4*4];
    }
    __syncthreads();

    const int h4 = t & 31, rg = t >> 5;
    const int r0 = rg * 2;
    float4 c0 = make_float4(0,0,0,0), c1 = c0;

#pragma unroll 2
    for (int d0 = 0; d0 < D_; d0 += 4) {
        float4 x0 = *(const float4*)&Xs[r0][d0];
        float4 x1 = *(const float4*)&Xs[r0+1][d0];
        float4 w0 = *(const float4*)&WT[(size_t)(d0+0) * H_ + h4*4];
        float4 w1 = *(const float4*)&WT[(size_t)(d0+1) * H_ + h4*4];
        float4 w2 = *(const float4*)&WT[(size_t)(d0+2) * H_ + h4*4];
        float4 w3 = *(const float4*)&WT[(size_t)(d0+3) * H_ + h4*4];
        c0.x += x0.x*w0.x + x0.y*w1.x + x0.z*w2.x + x0.w*w3.x;
        c0.y += x0.x*w0.y + x0.y*w1.y + x0.z*w2.y + x0.w*w3.y;
        c0.z += x0.x*w0.z + x0.y*w1.z + x0.z*w2.z + x0.w*w3.z;
        c0.w += x0.x*w0.w + x0.y*w1.w + x0.z*w2.w + x0.w*w3.w;
        c1.x += x1.x*w0.x + x1.y*w1.x + x1.z*w2.x + x1.w*w3.x;
        c1.y += x1.x*w0.y + x1.y*w1.y + x1.z*w2.y + x1.w*w3.y;
        c1.z += x1.x*w0.z + x1.y*w1.z + x1.z*w2.z + x1.w*w3.z;
        c1.w += x1.x*w0.w + x1.y*w1.w + x1.z*w2.w + x1.w*w3.w;
    }
    c0.x *= SCALE; c0.y *= SCALE; c0.z *= SCALE; c0.w *= SCALE;
    c1.x *= SCALE; c1.y *= SCALE; c1.z *= SCALE; c1.w *= SCALE;

    if (isQ) {
        *(float4*)&qh_s[(size_t)(R0 + r0)     * H_ + h4*4] = c0;
        *(float4*)&qh_s[(size_t)(R0 + r0 + 1) * H_ + h4*4] = c1;
    } else {
        kh4[(size_t)(b*32 + h4) * K_ + R0 + r0]     = c0;
        kh4[(size_t)(b*32 + h4) * K_ + R0 + r0 + 1] = c1;
    }
}

// ---------------------------------------------------------------------------
// attn_part: one (b, 4-q tile, 128-k chunk). Grid 2048 = [qt:64][b:4][kc:8],
// 256 thr (4 waves). Chunks past valid_len exit. No softmax max-pass
// (|score| <= Sum|w_v|, exp2 safe; softmax shift-invariant -> identical).
// Phase B: t = k(0..127) + 128*hh; hh-halves split the 32 hq into 16 each,
//          combined through LDS. e = exp2(C - 2log2e*acc), masked lanes -> 0.
// Phase D: col = t&127, k-half = t>>7 (64 k each); p broadcast from LDS,
//          v streamed from L2; halves combined in LDS; plain coalesced store
//          into private slice o_part[kc]. Row sums -> s_part[row][kc].
// finalize sums ceil(vl/128) slices. No atomics anywhere.
// ---------------------------------------------------------------------------
__global__ __launch_bounds__(256) void attn_part(
    const float* __restrict__ qh_s, const float4* __restrict__ kh4,
    const float* __restrict__ wvg,  const int* __restrict__ valid_lens,
    const float* __restrict__ vin,
    float* __restrict__ s_part, float4* __restrict__ o_part)
{
    __shared__ float  qv[512];
    __shared__ float  wvs[128];
    __shared__ float  ptmp[4][128];
    __shared__ float  p[4][128];
    __shared__ float  sred[2][4];
    __shared__ float4 otmp[4][128];

    const int t   = threadIdx.x;
    const int bid = blockIdx.x;
    const int kc  = bid & 7, b = (bid >> 3) & 3, qt = bid >> 5;
    const int q0  = qt * 4;
    const int vl  = valid_lens[b];
    const int kbase = kc * 128;
    if (kbase >= vl) return;
    const int klen = min(128, vl - kbase);

    qv[t]       = qh_s[(size_t)(b*Q_ + q0) * H_ + t];
    qv[t + 256] = qh_s[(size_t)(b*Q_ + q0) * H_ + t + 256];
    if (t < 128) wvs[t] = wvg[t];
    __syncthreads();

    const int k   = t & 127;            // k within chunk
    const int hh  = t >> 7;             // h-half
    const bool active = k < klen;

    // ---- Phase B: scores (h-split) ----
    float acc[4] = {0.f, 0.f, 0.f, 0.f};
    if (active) {
        const float4* khb = kh4 + (size_t)b * 32 * K_ + (kbase + k);
        const int hq0 = hh * 16;
#pragma unroll
        for (int hq = hq0; hq < hq0 + 16; ++hq) {
            float kx[4], w4[4], q4[4][4];
            *(float4*)&kx[0] = khb[(size_t)hq * K_];
            *(float4*)&w4[0] = *(const float4*)&wvs[hq*4];
#pragma unroll
            for (int qi = 0; qi < 4; ++qi)
                *(float4*)&q4[qi][0] = *(const float4*)&qv[qi*128 + hq*4];
#pragma unroll
            for (int j = 0; j < 4; ++j)
#pragma unroll
                for (int qi = 0; qi < 4; ++qi)
                    acc[qi] += w4[j] * sigl(q4[qi][j] + kx[j]);
        }
    }
    if (hh == 1) {
#pragma unroll
        for (int qi = 0; qi < 4; ++qi) ptmp[qi][k] = acc[qi];
    }
    __syncthreads();

    float wsum = 0.f;
#pragma unroll
    for (int i = 0; i < 32; ++i) {
        float4 w = *(const float4*)&wvs[i*4];
        wsum += w.x + w.y + w.z + w.w;
    }
    const float C = wsum * LOG2E;

    float psum[4] = {0.f, 0.f, 0.f, 0.f};
    if (hh == 0) {
#pragma unroll
        for (int qi = 0; qi < 4; ++qi) {
            float a = acc[qi] + ptmp[qi][k];
            float e = active ? __builtin_amdgcn_exp2f(fmaf(a, N2LOG2E, C)) : 0.f;
            p[qi][k] = e;
            psum[qi] = e;
        }
#pragma unroll
        for (int off = 32; off > 0; off >>= 1)
#pragma unroll
            for (int qi = 0; qi < 4; ++qi) psum[qi] += __shfl_xor(psum[qi], off);
        if ((t & 63) == 0) {
#pragma unroll
            for (int qi = 0; qi < 4; ++qi) sred[t >> 6][qi] = psum[qi];
        }
    }
    __syncthreads();                    // p + sred ready
    if (t < 4)
        s_part[(size_t)(b*Q_ + q0 + t) * 8 + kc] = sred[0][t] + sred[1][t];

    // ---- Phase D: partial PV ----
    const int col  = t & 127;           // float4 column of DV/4
    const int half = t >> 7;
    const int kb2  = half * 64;
    const int ke2  = min(klen, kb2 + 64);
    const float4* vb = (const float4*)vin + (size_t)b * K_ * 128 + (size_t)kbase * 128;

    float4 o0 = make_float4(0,0,0,0), o1 = o0, o2 = o0, o3 = o0;
    int kk = kb2;
#define PVACC(oq, pq) \
    oq.x += pq.x*v0.x + pq.y*v1.x + pq.z*v2.x + pq.w*v3.x; \
    oq.y += pq.x*v0.y + pq.y*v1.y + pq.z*v2.y + pq.w*v3.y; \
    oq.z += pq.x*v0.z + pq.y*v1.z + pq.z*v2.z + pq.w*v3.z; \
    oq.w += pq.x*v0.w + pq.y*v1.w + pq.z*v2.w + pq.w*v3.w;
    for (; kk + 4 <= ke2; kk += 4) {
        float4 p0 = *(const float4*)&p[0][kk];
        float4 p1 = *(const float4*)&p[1][kk];
        float4 p2 = *(const float4*)&p[2][kk];
        float4 p3 = *(const float4*)&p[3][kk];
        float4 v0 = vb[(size_t)(kk+0)*128 + col];
        float4 v1 = vb[(size_t)(kk+1)*128 + col];
        float4 v2 = vb[(size_t)(kk+2)*128 + col];
        float4 v3 = vb[(size_t)(kk+3)*128 + col];
        PVACC(o0, p0) PVACC(o1, p1) PVACC(o2, p2) PVACC(o3, p3)
    }
#undef PVACC
    for (; kk < ke2; ++kk) {
        float4 v0 = vb[(size_t)kk*128 + col];
        float pk;
        pk = p[0][kk]; o0.x += pk*v0.x; o0.y += pk*v0.y; o0.z += pk*v0.z; o0.w += pk*v0.w;
        pk = p[1][kk]; o1.x += pk*v0.x; o1.y += pk*v0.y; o1.z += pk*v0.z; o1.w += pk*v0.w;
        pk = p[2][kk]; o2.x += pk*v0.x; o2.y += pk*v0.y; o2.z += pk*v0.z; o2.w += pk*v0.w;
        pk = p[3][kk]; o3.x += pk*v0.x; o3.y += pk*v0.y; o3.z += pk*v0.z; o3.w += pk*v0.w;
    }

    if (half == 1) {
        otmp[0][col] = o0; otmp[1][col] = o1; otmp[2][col] = o2; otmp[3][col] = o3;
    }
    __syncthreads();
    if (half == 0) {
        float4 r;
        r = otmp[0][col]; o0.x += r.x; o0.y += r.y; o0.z += r.z; o0.w += r.w;
        r = otmp[1][col]; o1.x += r.x; o1.y += r.y; o1.z += r.z; o1.w += r.w;
        r = otmp[2][col]; o2.x += r.x; o2.y += r.y; o2.z += r.z; o2.w += r.w;
        r = otmp[3][col]; o3.x += r.x; o3.y += r.y; o3.z += r.z; o3.w += r.w;
        float4 os[4] = {o0, o1, o2, o3};
#pragma unroll
        for (int qi = 0; qi < 4; ++qi)
            o_part[((size_t)kc * 1024 + (b*Q_ + q0 + qi)) * 128 + col] = os[qi];
    }
}

// ---------------------------------------------------------------------------
// finalize: out[row][col] = (Sum_{ch<nch} o_part[ch][row][col]) * rcp(Sum s).
// ---------------------------------------------------------------------------
__global__ __launch_bounds__(256) void finalize_kernel(
    const float4* __restrict__ o_part, const float* __restrict__ s_part,
    const int* __restrict__ valid_lens, float4* __restrict__ out)
{
    int gid = blockIdx.x * 256 + threadIdx.x;     // [0, 131072)
    int row = gid >> 7, col = gid & 127;
    int b = row >> 8;
    int nch = (valid_lens[b] + 127) >> 7;
    float ssum = 0.f;
    float4 o = make_float4(0,0,0,0);
    for (int ch = 0; ch < nch; ++ch) {
        ssum += s_part[(size_t)row * 8 + ch];
        float4 r = o_part[((size_t)ch * 1024 + row) * 128 + col];
        o.x += r.x; o.y += r.y; o.z += r.z; o.w += r.w;
    }
    float rs = __builtin_amdgcn_rcpf(ssum);
    out[gid] = make_float4(o.x*rs, o.y*rs, o.z*rs, o.w*rs);
}

extern "C" void kernel_launch(void* const* d_in, const int* in_sizes, int n_in,
                              void* d_out, int out_size, void* d_ws, size_t ws_size,
                              hipStream_t stream)
{
    const float* q  = (const float*)d_in[0];
    const float* k  = (const float*)d_in[1];
    const float* v  = (const float*)d_in[2];
    const int*   vl = (const int*)d_in[3];
    const float* wq = (const float*)d_in[4];
    const float* wk = (const float*)d_in[5];
    const float* wv = (const float*)d_in[6];
    float* out = (float*)d_out;

    float* wt_q  = (float*)d_ws;                      //   65536 f
    float* wt_k  = wt_q  + D_*H_;                     //   65536 f
    float* qh_s  = wt_k  + D_*H_;                     //  131072 f
    float* kh4   = qh_s  + (size_t)B_*Q_*H_;          //  524288 f
    float* s_prt = kh4   + (size_t)B_*H_*K_;          //    8192 f
    float* o_prt = s_prt + (size_t)B_*Q_*8;           // 4194304 f (16 MB)

    transpose_w    <<<dim3(16),   dim3(256), 0, stream>>>(wq, wk, wt_q, wt_k);
    proj2_kernel   <<<dim3(320),  dim3(256), 0, stream>>>(q, k, wt_q, wt_k, vl, qh_s, (float4*)kh4);
    attn_part      <<<dim3(2048), dim3(256), 0, stream>>>(qh_s, (const float4*)kh4, wv, vl, v, s_prt, (float4*)o_prt);
    finalize_kernel<<<dim3(512),  dim3(256), 0, stream>>>((const float4*)o_prt, s_prt, vl, (float4*)out);
}

// Round 7
// 138.399 us; speedup vs baseline: 1.5278x; 1.1025x over previous
//
#include <hip/hip_runtime.h>

// AdditiveAttention: B=4, Q=256, K=1024, DQ=DK=DV=512, H=128
#define B_ 4
#define Q_ 256
#define K_ 1024
#define D_ 512
#define H_ 128
#define DV_ 512
#define SCALE 2.885390081777927f    // 2*log2(e): tanh(x)=1-2/(exp2(S*x)+1)
#define LOG2E 1.4426950408889634f
#define N2LOG2E (-2.0f * 1.4426950408889634f)

// rcp(exp2(x)+1); Sum_h w*tanh = wsum - 2*Sum_h w*sigl
__device__ __forceinline__ float sigl(float x) {
    return __builtin_amdgcn_rcpf(__builtin_amdgcn_exp2f(x) + 1.0f);
}

// ---------------------------------------------------------------------------
// transpose_w: WT[d][h] = W[h][d] for wq and wk. 16 blocks = [m:2][dt:8].
// ---------------------------------------------------------------------------
__global__ __launch_bounds__(256) void transpose_w(
    const float* __restrict__ wq, const float* __restrict__ wk,
    float* __restrict__ wt_q, float* __restrict__ wt_k)
{
    __shared__ float Ts[64][133];
    const int t = threadIdx.x, bid = blockIdx.x;
    const int m = bid >> 3, d0 = (bid & 7) * 64;
    const float* W  = m ? wk : wq;
    float*       WT = m ? wt_k : wt_q;
#pragma unroll
    for (int i = 0; i < 8; ++i) {
        int idx = i * 256 + t;
        int h = idx >> 4, dq = idx & 15;
        float4 v = *(const float4*)&W[(size_t)h * D_ + d0 + dq*4];
        Ts[dq*4+0][h] = v.x; Ts[dq*4+1][h] = v.y;
        Ts[dq*4+2][h] = v.z; Ts[dq*4+3][h] = v.w;
    }
    __syncthreads();
#pragma unroll
    for (int i = 0; i < 8; ++i) {
        int idx = i * 256 + t;
        int d = idx >> 5, h4 = idx & 31;
        *(float4*)&WT[(size_t)(d0 + d) * H_ + h4*4] = *(const float4*)&Ts[d][h4*4];
    }
}

// ---------------------------------------------------------------------------
// proj2: 16 rows x 128 h per block, 256 thr. WT read coalesced (L2-resident,
// prefetched one d-group ahead), X-tile broadcast from LDS.
//   qh_s[row][h]         (blocks 0..63)
//   kh4[b][h>>2][k][h&3] (blocks 64..319, tiles past valid_len skipped)
// ---------------------------------------------------------------------------
__global__ __launch_bounds__(256) void proj2_kernel(
    const float* __restrict__ qin, const float* __restrict__ kin,
    const float* __restrict__ wt_q, const float* __restrict__ wt_k,
    const int* __restrict__ valid_lens,
    float* __restrict__ qh_s, float4* __restrict__ kh4)
{
    __shared__ float Xs[16][512];    // 32 KB

    const int t = threadIdx.x, bid = blockIdx.x;
    const bool isQ = bid < 64;
    const float* X; const float* WT; int R0; int b = 0;
    if (isQ) { X = qin; WT = wt_q; R0 = bid * 16; }
    else {
        int kb = bid - 64;
        b  = kb >> 6;
        R0 = (kb & 63) * 16;
        if (R0 >= valid_lens[b]) return;
        X = kin + (size_t)b * K_ * D_;
        WT = wt_k;
    }

#pragma unroll
    for (int i = 0; i < 8; ++i) {       // stage 16x512 X tile
        int idx = i * 256 + t;
        int row = idx >> 7, d4 = idx & 127;
        *(float4*)&Xs[row][d4*4] = *(const float4*)&X[(size_t)(R0 + row) * D_ + d4*4];
    }
    __syncthreads();

    const int h4 = t & 31, rg = t >> 5;
    const int r0 = rg * 2;
    float4 c0 = make_float4(0,0,0,0), c1 = c0;

    const float* WTh = WT + h4*4;
    float4 w0 = *(const float4*)&WTh[0*H_];
    float4 w1 = *(const float4*)&WTh[1*H_];
    float4 w2 = *(const float4*)&WTh[2*H_];
    float4 w3 = *(const float4*)&WTh[3*H_];

#pragma unroll 2
    for (int d0 = 0; d0 < D_; d0 += 4) {
        float4 u0 = w0, u1 = w1, u2 = w2, u3 = w3;
        int dn = (d0 + 4 < D_) ? d0 + 4 : d0;     // clamped prefetch
        w0 = *(const float4*)&WTh[(size_t)(dn+0) * H_];
        w1 = *(const float4*)&WTh[(size_t)(dn+1) * H_];
        w2 = *(const float4*)&WTh[(size_t)(dn+2) * H_];
        w3 = *(const float4*)&WTh[(size_t)(dn+3) * H_];
        float4 x0 = *(const float4*)&Xs[r0][d0];
        float4 x1 = *(const float4*)&Xs[r0+1][d0];
        c0.x += x0.x*u0.x + x0.y*u1.x + x0.z*u2.x + x0.w*u3.x;
        c0.y += x0.x*u0.y + x0.y*u1.y + x0.z*u2.y + x0.w*u3.y;
        c0.z += x0.x*u0.z + x0.y*u1.z + x0.z*u2.z + x0.w*u3.z;
        c0.w += x0.x*u0.w + x0.y*u1.w + x0.z*u2.w + x0.w*u3.w;
        c1.x += x1.x*u0.x + x1.y*u1.x + x1.z*u2.x + x1.w*u3.x;
        c1.y += x1.x*u0.y + x1.y*u1.y + x1.z*u2.y + x1.w*u3.y;
        c1.z += x1.x*u0.z + x1.y*u1.z + x1.z*u2.z + x1.w*u3.z;
        c1.w += x1.x*u0.w + x1.y*u1.w + x1.z*u2.w + x1.w*u3.w;
    }
    c0.x *= SCALE; c0.y *= SCALE; c0.z *= SCALE; c0.w *= SCALE;
    c1.x *= SCALE; c1.y *= SCALE; c1.z *= SCALE; c1.w *= SCALE;

    if (isQ) {
        *(float4*)&qh_s[(size_t)(R0 + r0)     * H_ + h4*4] = c0;
        *(float4*)&qh_s[(size_t)(R0 + r0 + 1) * H_ + h4*4] = c1;
    } else {
        kh4[(size_t)(b*32 + h4) * K_ + R0 + r0]     = c0;
        kh4[(size_t)(b*32 + h4) * K_ + R0 + r0 + 1] = c1;
    }
}

// ---------------------------------------------------------------------------
// attn_part: one (b, 4-q tile, 128-k chunk). Grid 2048, 256 thr (4 waves).
// Block mapping: qt = bid&63 (fastest) so the round-robin workgroup->XCD
// assignment spreads every (b,kc) chunk evenly across XCDs — the round-6
// layout had kc == bid&7 == XCD index, concentrating all work of a chunk
// (and all early-exit blocks) on single XCDs.
// No softmax max-pass (|score| <= Sum|w_v| ~ 5, exp2 safe; shift-invariant).
// Phase B: hh-halves split 32 hq; kh prefetched 1 hq ahead (L2 ~300 cyc).
// Phase D: col=t&127, k-half=t>>7; v prefetched one 4-group ahead; p
//          broadcast from LDS; plain stores into private slice o_part[kc].
// ---------------------------------------------------------------------------
__global__ __launch_bounds__(256) void attn_part(
    const float* __restrict__ qh_s, const float4* __restrict__ kh4,
    const float* __restrict__ wvg,  const int* __restrict__ valid_lens,
    const float* __restrict__ vin,
    float* __restrict__ s_part, float4* __restrict__ o_part)
{
    __shared__ float  qv[512];
    __shared__ float  wvs[128];
    __shared__ float  ptmp[4][128];
    __shared__ float  p[4][128];
    __shared__ float  sred[2][4];
    __shared__ float4 otmp[4][128];

    const int t   = threadIdx.x;
    const int bid = blockIdx.x;
    const int qt  = bid & 63, b = (bid >> 6) & 3, kc = bid >> 8;
    const int q0  = qt * 4;
    const int vl  = valid_lens[b];
    const int kbase = kc * 128;
    if (kbase >= vl) return;
    const int klen = min(128, vl - kbase);

    qv[t]       = qh_s[(size_t)(b*Q_ + q0) * H_ + t];
    qv[t + 256] = qh_s[(size_t)(b*Q_ + q0) * H_ + t + 256];
    if (t < 128) wvs[t] = wvg[t];
    __syncthreads();

    const int k   = t & 127;            // k within chunk
    const int hh  = t >> 7;             // h-half
    const bool active = k < klen;

    // ---- Phase B: scores (h-split, kh prefetch depth 1) ----
    float acc[4] = {0.f, 0.f, 0.f, 0.f};
    if (active) {
        const float4* khp = kh4 + (size_t)b * 32 * K_ + (kbase + k)
                          + (size_t)(hh * 16) * K_;
        const int hq0 = hh * 16;
        float4 kxn = khp[0];
#pragma unroll 4
        for (int i = 0; i < 16; ++i) {
            float4 kx = kxn;
            int ni = (i < 15) ? i + 1 : 15;
            kxn = khp[(size_t)ni * K_];
            const int hq = hq0 + i;
            float w4[4], q4[4][4];
            *(float4*)&w4[0] = *(const float4*)&wvs[hq*4];
#pragma unroll
            for (int qi = 0; qi < 4; ++qi)
                *(float4*)&q4[qi][0] = *(const float4*)&qv[qi*128 + hq*4];
            float kxa[4];
            *(float4*)&kxa[0] = kx;
#pragma unroll
            for (int j = 0; j < 4; ++j)
#pragma unroll
                for (int qi = 0; qi < 4; ++qi)
                    acc[qi] += w4[j] * sigl(q4[qi][j] + kxa[j]);
        }
    }
    if (hh == 1) {
#pragma unroll
        for (int qi = 0; qi < 4; ++qi) ptmp[qi][k] = acc[qi];
    }
    __syncthreads();

    float wsum = 0.f;
#pragma unroll
    for (int i = 0; i < 32; ++i) {
        float4 w = *(const float4*)&wvs[i*4];
        wsum += w.x + w.y + w.z + w.w;
    }
    const float C = wsum * LOG2E;

    float psum[4] = {0.f, 0.f, 0.f, 0.f};
    if (hh == 0) {
#pragma unroll
        for (int qi = 0; qi < 4; ++qi) {
            float a = acc[qi] + ptmp[qi][k];
            float e = active ? __builtin_amdgcn_exp2f(fmaf(a, N2LOG2E, C)) : 0.f;
            p[qi][k] = e;
            psum[qi] = e;
        }
#pragma unroll
        for (int off = 32; off > 0; off >>= 1)
#pragma unroll
            for (int qi = 0; qi < 4; ++qi) psum[qi] += __shfl_xor(psum[qi], off);
        if ((t & 63) == 0) {
#pragma unroll
            for (int qi = 0; qi < 4; ++qi) sred[t >> 6][qi] = psum[qi];
        }
    }
    __syncthreads();                    // p + sred ready
    if (t < 4)
        s_part[(size_t)(b*Q_ + q0 + t) * 8 + kc] = sred[0][t] + sred[1][t];

    // ---- Phase D: partial PV (v prefetch depth one 4-group) ----
    const int col  = t & 127;           // float4 column of DV/4
    const int half = t >> 7;
    const int kb2  = half * 64;
    const int ke2  = min(klen, kb2 + 64);
    const float4* vb = (const float4*)vin + (size_t)b * K_ * 128 + (size_t)kbase * 128;

    float4 o0 = make_float4(0,0,0,0), o1 = o0, o2 = o0, o3 = o0;
    int kk = kb2;
    const int nfull = (ke2 > kb2) ? ((ke2 - kb2) >> 2) : 0;
#define PVACC(oq, pq) \
    oq.x += pq.x*v0.x + pq.y*v1.x + pq.z*v2.x + pq.w*v3.x; \
    oq.y += pq.x*v0.y + pq.y*v1.y + pq.z*v2.y + pq.w*v3.y; \
    oq.z += pq.x*v0.z + pq.y*v1.z + pq.z*v2.z + pq.w*v3.z; \
    oq.w += pq.x*v0.w + pq.y*v1.w + pq.z*v2.w + pq.w*v3.w;
    if (nfull > 0) {
        float4 n0 = vb[(size_t)(kk+0)*128 + col];
        float4 n1 = vb[(size_t)(kk+1)*128 + col];
        float4 n2 = vb[(size_t)(kk+2)*128 + col];
        float4 n3 = vb[(size_t)(kk+3)*128 + col];
        for (int g = 0; g < nfull; ++g) {
            float4 v0 = n0, v1 = n1, v2 = n2, v3 = n3;
            int kn = kk + 4;
            if (g + 1 < nfull) {
                n0 = vb[(size_t)(kn+0)*128 + col];
                n1 = vb[(size_t)(kn+1)*128 + col];
                n2 = vb[(size_t)(kn+2)*128 + col];
                n3 = vb[(size_t)(kn+3)*128 + col];
            }
            float4 p0 = *(const float4*)&p[0][kk];
            float4 p1 = *(const float4*)&p[1][kk];
            float4 p2 = *(const float4*)&p[2][kk];
            float4 p3 = *(const float4*)&p[3][kk];
            PVACC(o0, p0) PVACC(o1, p1) PVACC(o2, p2) PVACC(o3, p3)
            kk = kn;
        }
    }
#undef PVACC
    for (; kk < ke2; ++kk) {
        float4 v0 = vb[(size_t)kk*128 + col];
        float pk;
        pk = p[0][kk]; o0.x += pk*v0.x; o0.y += pk*v0.y; o0.z += pk*v0.z; o0.w += pk*v0.w;
        pk = p[1][kk]; o1.x += pk*v0.x; o1.y += pk*v0.y; o1.z += pk*v0.z; o1.w += pk*v0.w;
        pk = p[2][kk]; o2.x += pk*v0.x; o2.y += pk*v0.y; o2.z += pk*v0.z; o2.w += pk*v0.w;
        pk = p[3][kk]; o3.x += pk*v0.x; o3.y += pk*v0.y; o3.z += pk*v0.z; o3.w += pk*v0.w;
    }

    if (half == 1) {
        otmp[0][col] = o0; otmp[1][col] = o1; otmp[2][col] = o2; otmp[3][col] = o3;
    }
    __syncthreads();
    if (half == 0) {
        float4 r;
        r = otmp[0][col]; o0.x += r.x; o0.y += r.y; o0.z += r.z; o0.w += r.w;
        r = otmp[1][col]; o1.x += r.x; o1.y += r.y; o1.z += r.z; o1.w += r.w;
        r = otmp[2][col]; o2.x += r.x; o2.y += r.y; o2.z += r.z; o2.w += r.w;
        r = otmp[3][col]; o3.x += r.x; o3.y += r.y; o3.z += r.z; o3.w += r.w;
        float4 os[4] = {o0, o1, o2, o3};
#pragma unroll
        for (int qi = 0; qi < 4; ++qi)
            o_part[((size_t)kc * 1024 + (b*Q_ + q0 + qi)) * 128 + col] = os[qi];
    }
}

// ---------------------------------------------------------------------------
// finalize: out[row][col] = (Sum_{ch<nch} o_part[ch][row][col]) * rcp(Sum s).
// ---------------------------------------------------------------------------
__global__ __launch_bounds__(256) void finalize_kernel(
    const float4* __restrict__ o_part, const float* __restrict__ s_part,
    const int* __restrict__ valid_lens, float4* __restrict__ out)
{
    int gid = blockIdx.x * 256 + threadIdx.x;     // [0, 131072)
    int row = gid >> 7, col = gid & 127;
    int b = row >> 8;
    int nch = (valid_lens[b] + 127) >> 7;
    float ssum = 0.f;
    float4 o = make_float4(0,0,0,0);
    for (int ch = 0; ch < nch; ++ch) {
        ssum += s_part[(size_t)row * 8 + ch];
        float4 r = o_part[((size_t)ch * 1024 + row) * 128 + col];
        o.x += r.x; o.y += r.y; o.z += r.z; o.w += r.w;
    }
    float rs = __builtin_amdgcn_rcpf(ssum);
    out[gid] = make_float4(o.x*rs, o.y*rs, o.z*rs, o.w*rs);
}

extern "C" void kernel_launch(void* const* d_in, const int* in_sizes, int n_in,
                              void* d_out, int out_size, void* d_ws, size_t ws_size,
                              hipStream_t stream)
{
    const float* q  = (const float*)d_in[0];
    const float* k  = (const float*)d_in[1];
    const float* v  = (const float*)d_in[2];
    const int*   vl = (const int*)d_in[3];
    const float* wq = (const float*)d_in[4];
    const float* wk = (const float*)d_in[5];
    const float* wv = (const float*)d_in[6];
    float* out = (float*)d_out;

    float* wt_q  = (float*)d_ws;                      //   65536 f
    float* wt_k  = wt_q  + D_*H_;                     //   65536 f
    float* qh_s  = wt_k  + D_*H_;                     //  131072 f
    float* kh4   = qh_s  + (size_t)B_*Q_*H_;          //  524288 f
    float* s_prt = kh4   + (size_t)B_*H_*K_;          //    8192 f
    float* o_prt = s_prt + (size_t)B_*Q_*8;           // 4194304 f (16 MB)

    transpose_w    <<<dim3(16),   dim3(256), 0, stream>>>(wq, wk, wt_q, wt_k);
    proj2_kernel   <<<dim3(320),  dim3(256), 0, stream>>>(q, k, wt_q, wt_k, vl, qh_s, (float4*)kh4);
    attn_part      <<<dim3(2048), dim3(256), 0, stream>>>(qh_s, (const float4*)kh4, wv, vl, v, s_prt, (float4*)o_prt);
    finalize_kernel<<<dim3(512),  dim3(256), 0, stream>>>((const float4*)o_prt, s_prt, vl, (float4*)out);
}

// Round 8
// 133.594 us; speedup vs baseline: 1.5828x; 1.0360x over previous
//
#include <hip/hip_runtime.h>

// AdditiveAttention: B=4, Q=256, K=1024, DQ=DK=DV=512, H=128
#define B_ 4
#define Q_ 256
#define K_ 1024
#define D_ 512
#define H_ 128
#define DV_ 512
#define SCALE 2.885390081777927f    // 2*log2(e): tanh(x)=1-2/(exp2(S*x)+1)
#define LOG2E 1.4426950408889634f
#define N2LOG2E (-2.0f * 1.4426950408889634f)

// rcp(exp2(x)+1); Sum_h w*tanh = wsum - 2*Sum_h w*sigl
__device__ __forceinline__ float sigl(float x) {
    return __builtin_amdgcn_rcpf(__builtin_amdgcn_exp2f(x) + 1.0f);
}

// ---------------------------------------------------------------------------
// proj_part: one (128-row tile, 64-d slice). Grid 320 = [tile:40 fastest][ds:8].
// tile<8: q rows; tile>=8: k rows (tile-8 -> b = kt>>3, kr=(kt&7)*128), masked
// tiles exit. Global row R0 = tile*128 uniformly (q rows 0..1023, k rows
// 1024..5119). Stage Xs[64d][128r] + Ws[64d][128h] (68 KB, 2 blocks/CU),
// ONE barrier, then 4 waves = 64x64 quadrants, lane micro 8x8 (all LDS reads
// b128, 2-way-or-broadcast bank pattern = free). Partials -> psum[ds] slice.
// No atomics: every active (row,ds) written exactly once.
// ---------------------------------------------------------------------------
__global__ __launch_bounds__(256) void proj_part(
    const float* __restrict__ qin, const float* __restrict__ kin,
    const float* __restrict__ wq,  const float* __restrict__ wk,
    const int* __restrict__ valid_lens, float* __restrict__ psum)
{
    __shared__ float Xs[64][132];    // 33.8 KB
    __shared__ float Ws[64][132];    // 33.8 KB

    const int t = threadIdx.x, bid = blockIdx.x;
    const int tile = bid % 40, ds = bid / 40;
    const int d0 = ds * 64;
    const float* X; const float* W;
    if (tile < 8) { X = qin + (size_t)tile * 128 * D_; W = wq; }
    else {
        int kt = tile - 8, b = kt >> 3, kr = (kt & 7) * 128;
        if (kr >= valid_lens[b]) return;
        X = kin + ((size_t)b * K_ + kr) * D_;
        W = wk;
    }
    const int R0 = tile * 128;

#pragma unroll
    for (int i = 0; i < 8; ++i) {        // stage X: 128 r x 64 d
        int idx = t + i * 256;
        int row = idx >> 4, dq = (idx & 15) * 4;
        float4 xv = *(const float4*)&X[(size_t)row * D_ + d0 + dq];
        Xs[dq+0][row] = xv.x; Xs[dq+1][row] = xv.y;
        Xs[dq+2][row] = xv.z; Xs[dq+3][row] = xv.w;
    }
#pragma unroll
    for (int i = 0; i < 8; ++i) {        // stage W: 128 h x 64 d
        int idx = t + i * 256;
        int h = idx >> 4, dq = (idx & 15) * 4;
        float4 wv = *(const float4*)&W[(size_t)h * D_ + d0 + dq];
        Ws[dq+0][h] = wv.x; Ws[dq+1][h] = wv.y;
        Ws[dq+2][h] = wv.z; Ws[dq+3][h] = wv.w;
    }
    __syncthreads();

    const int wid = t >> 6, lane = t & 63;
    const int r0 = (wid >> 1) * 64 + (lane >> 3) * 8;
    const int h0 = (wid & 1)  * 64 + (lane & 7)  * 8;
    float c[8][8] = {};

#pragma unroll 8
    for (int kk = 0; kk < 64; ++kk) {
        float xr[8], wr[8];
        *(float4*)&xr[0] = *(const float4*)&Xs[kk][r0];
        *(float4*)&xr[4] = *(const float4*)&Xs[kk][r0 + 4];
        *(float4*)&wr[0] = *(const float4*)&Ws[kk][h0];
        *(float4*)&wr[4] = *(const float4*)&Ws[kk][h0 + 4];
#pragma unroll
        for (int i = 0; i < 8; ++i)
#pragma unroll
            for (int j = 0; j < 8; ++j) c[i][j] += xr[i] * wr[j];
    }

    float* outp = psum + ((size_t)ds * 5120 + R0) * 128;
#pragma unroll
    for (int i = 0; i < 8; ++i) {
        *(float4*)&outp[(size_t)(r0 + i) * 128 + h0]     = *(const float4*)&c[i][0];
        *(float4*)&outp[(size_t)(r0 + i) * 128 + h0 + 4] = *(const float4*)&c[i][4];
    }
}

// ---------------------------------------------------------------------------
// proj_reduce: sum 8 d-slices, apply SCALE, write qh_s / kh4 layouts.
// 640 blocks x 256 thr; gid = row*32 + c4 (f4 column). Masked k rows skipped
// (their kh4 is never read).
// ---------------------------------------------------------------------------
__global__ __launch_bounds__(256) void proj_reduce(
    const float* __restrict__ psum, const int* __restrict__ valid_lens,
    float* __restrict__ qh_s, float4* __restrict__ kh4)
{
    int gid = blockIdx.x * 256 + threadIdx.x;    // [0, 163840)
    int row = gid >> 5, c4 = gid & 31;
    int b = 0, kk = 0;
    if (row >= 1024) {
        int r = row - 1024;
        b = r >> 10; kk = r & 1023;
        if (kk >= valid_lens[b]) return;
    }
    float4 s = make_float4(0.f, 0.f, 0.f, 0.f);
#pragma unroll
    for (int ds = 0; ds < 8; ++ds) {
        float4 v = *(const float4*)&psum[((size_t)ds * 5120 + row) * 128 + c4 * 4];
        s.x += v.x; s.y += v.y; s.z += v.z; s.w += v.w;
    }
    s.x *= SCALE; s.y *= SCALE; s.z *= SCALE; s.w *= SCALE;
    if (row < 1024) *(float4*)&qh_s[(size_t)row * 128 + c4 * 4] = s;
    else            kh4[((size_t)(b * 32 + c4)) * K_ + kk] = s;
}

// ---------------------------------------------------------------------------
// attn_part: one (b, 8-q tile, 128-k chunk). Grid 1024 = [qt:32 fastest]
// [b:4][kc:8], 256 thr (4 waves). qt fastest keeps every (b,kc) spread
// across XCDs. No softmax max-pass (|score| <= Sum|w_v|, exp2 safe;
// shift-invariant). Phase B: hh-halves split 32 hq, kh prefetch depth 1.
// Phase D: col=t&127, k-half=t>>7, v prefetch one 4-group ahead; p broadcast
// from LDS; plain stores into private slice o_part[kc]; s -> s_part.
// ---------------------------------------------------------------------------
__global__ __launch_bounds__(256) void attn_part(
    const float* __restrict__ qh_s, const float4* __restrict__ kh4,
    const float* __restrict__ wvg,  const int* __restrict__ valid_lens,
    const float* __restrict__ vin,
    float* __restrict__ s_part, float4* __restrict__ o_part)
{
    __shared__ float  qv[1024];
    __shared__ float  wvs[128];
    __shared__ float  ptmp[8][128];
    __shared__ float  p[8][128];
    __shared__ float  sred[2][8];
    __shared__ float4 otmp[8][128];

    const int t   = threadIdx.x;
    const int bid = blockIdx.x;
    const int qt  = bid & 31, b = (bid >> 5) & 3, kc = bid >> 7;
    const int q0  = qt * 8;
    const int vl  = valid_lens[b];
    const int kbase = kc * 128;
    if (kbase >= vl) return;
    const int klen = min(128, vl - kbase);

#pragma unroll
    for (int i = 0; i < 4; ++i)
        qv[t + i * 256] = qh_s[(size_t)(b*Q_ + q0) * H_ + t + i * 256];
    if (t < 128) wvs[t] = wvg[t];
    __syncthreads();

    const int k  = t & 127;             // k within chunk
    const int hh = t >> 7;              // h-half
    const bool active = k < klen;

    // ---- Phase B: scores (h-split, kh prefetch depth 1) ----
    float acc[8] = {};
    if (active) {
        const float4* khp = kh4 + (size_t)b * 32 * K_ + (kbase + k)
                          + (size_t)(hh * 16) * K_;
        const int hq0 = hh * 16;
        float4 kxn = khp[0];
#pragma unroll 4
        for (int i = 0; i < 16; ++i) {
            float4 kx = kxn;
            int ni = (i < 15) ? i + 1 : 15;
            kxn = khp[(size_t)ni * K_];
            const int hq = hq0 + i;
            float w4[4], kxa[4];
            *(float4*)&w4[0]  = *(const float4*)&wvs[hq*4];
            *(float4*)&kxa[0] = kx;
#pragma unroll
            for (int qi = 0; qi < 8; ++qi) {
                float q4[4];
                *(float4*)&q4[0] = *(const float4*)&qv[qi*128 + hq*4];
#pragma unroll
                for (int j = 0; j < 4; ++j)
                    acc[qi] += w4[j] * sigl(q4[j] + kxa[j]);
            }
        }
    }
    if (hh == 1) {
#pragma unroll
        for (int qi = 0; qi < 8; ++qi) ptmp[qi][k] = acc[qi];
    }
    __syncthreads();

    float wsum = 0.f;
#pragma unroll
    for (int i = 0; i < 32; ++i) {
        float4 w = *(const float4*)&wvs[i*4];
        wsum += w.x + w.y + w.z + w.w;
    }
    const float C = wsum * LOG2E;

    if (hh == 0) {
        float psum8[8];
#pragma unroll
        for (int qi = 0; qi < 8; ++qi) {
            float a = acc[qi] + ptmp[qi][k];
            float e = active ? __builtin_amdgcn_exp2f(fmaf(a, N2LOG2E, C)) : 0.f;
            p[qi][k] = e;
            psum8[qi] = e;
        }
#pragma unroll
        for (int off = 32; off > 0; off >>= 1)
#pragma unroll
            for (int qi = 0; qi < 8; ++qi) psum8[qi] += __shfl_xor(psum8[qi], off);
        if ((t & 63) == 0) {
#pragma unroll
            for (int qi = 0; qi < 8; ++qi) sred[t >> 6][qi] = psum8[qi];
        }
    }
    __syncthreads();                    // p + sred ready
    if (t < 8)
        s_part[(size_t)(b*Q_ + q0 + t) * 8 + kc] = sred[0][t] + sred[1][t];

    // ---- Phase D: partial PV (v prefetch one 4-group ahead) ----
    const int col  = t & 127;           // float4 column of DV/4
    const int half = t >> 7;
    const int kb2  = half * 64;
    const int ke2  = min(klen, kb2 + 64);
    const float4* vb = (const float4*)vin + (size_t)b * K_ * 128 + (size_t)kbase * 128;

    float4 o[8];
#pragma unroll
    for (int qi = 0; qi < 8; ++qi) o[qi] = make_float4(0.f, 0.f, 0.f, 0.f);

    int kk = kb2;
    const int nfull = (ke2 > kb2) ? ((ke2 - kb2) >> 2) : 0;
    if (nfull > 0) {
        float4 n0 = vb[(size_t)(kk+0)*128 + col];
        float4 n1 = vb[(size_t)(kk+1)*128 + col];
        float4 n2 = vb[(size_t)(kk+2)*128 + col];
        float4 n3 = vb[(size_t)(kk+3)*128 + col];
        for (int g = 0; g < nfull; ++g) {
            float4 v0 = n0, v1 = n1, v2 = n2, v3 = n3;
            int kn = kk + 4;
            if (g + 1 < nfull) {
                n0 = vb[(size_t)(kn+0)*128 + col];
                n1 = vb[(size_t)(kn+1)*128 + col];
                n2 = vb[(size_t)(kn+2)*128 + col];
                n3 = vb[(size_t)(kn+3)*128 + col];
            }
#pragma unroll
            for (int qi = 0; qi < 8; ++qi) {
                float4 pq = *(const float4*)&p[qi][kk];
                o[qi].x += pq.x*v0.x + pq.y*v1.x + pq.z*v2.x + pq.w*v3.x;
                o[qi].y += pq.x*v0.y + pq.y*v1.y + pq.z*v2.y + pq.w*v3.y;
                o[qi].z += pq.x*v0.z + pq.y*v1.z + pq.z*v2.z + pq.w*v3.z;
                o[qi].w += pq.x*v0.w + pq.y*v1.w + pq.z*v2.w + pq.w*v3.w;
            }
            kk = kn;
        }
    }
    for (; kk < ke2; ++kk) {
        float4 v0 = vb[(size_t)kk*128 + col];
#pragma unroll
        for (int qi = 0; qi < 8; ++qi) {
            float pk = p[qi][kk];
            o[qi].x += pk*v0.x; o[qi].y += pk*v0.y;
            o[qi].z += pk*v0.z; o[qi].w += pk*v0.w;
        }
    }

    if (half == 1) {
#pragma unroll
        for (int qi = 0; qi < 8; ++qi) otmp[qi][col] = o[qi];
    }
    __syncthreads();
    if (half == 0) {
#pragma unroll
        for (int qi = 0; qi < 8; ++qi) {
            float4 r = otmp[qi][col];
            o[qi].x += r.x; o[qi].y += r.y; o[qi].z += r.z; o[qi].w += r.w;
            o_part[((size_t)kc * 1024 + (b*Q_ + q0 + qi)) * 128 + col] = o[qi];
        }
    }
}

// ---------------------------------------------------------------------------
// finalize: out[row][col] = (Sum_{ch<nch} o_part[ch][row][col]) * rcp(Sum s).
// ---------------------------------------------------------------------------
__global__ __launch_bounds__(256) void finalize_kernel(
    const float4* __restrict__ o_part, const float* __restrict__ s_part,
    const int* __restrict__ valid_lens, float4* __restrict__ out)
{
    int gid = blockIdx.x * 256 + threadIdx.x;     // [0, 131072)
    int row = gid >> 7, col = gid & 127;
    int b = row >> 8;
    int nch = (valid_lens[b] + 127) >> 7;
    float ssum = 0.f;
    float4 o = make_float4(0.f, 0.f, 0.f, 0.f);
    for (int ch = 0; ch < nch; ++ch) {
        ssum += s_part[(size_t)row * 8 + ch];
        float4 r = o_part[((size_t)ch * 1024 + row) * 128 + col];
        o.x += r.x; o.y += r.y; o.z += r.z; o.w += r.w;
    }
    float rs = __builtin_amdgcn_rcpf(ssum);
    out[gid] = make_float4(o.x*rs, o.y*rs, o.z*rs, o.w*rs);
}

extern "C" void kernel_launch(void* const* d_in, const int* in_sizes, int n_in,
                              void* d_out, int out_size, void* d_ws, size_t ws_size,
                              hipStream_t stream)
{
    const float* q  = (const float*)d_in[0];
    const float* k  = (const float*)d_in[1];
    const float* v  = (const float*)d_in[2];
    const int*   vl = (const int*)d_in[3];
    const float* wq = (const float*)d_in[4];
    const float* wk = (const float*)d_in[5];
    const float* wv = (const float*)d_in[6];
    float* out = (float*)d_out;

    float* qh_s  = (float*)d_ws;                      //  131072 f
    float* kh4   = qh_s  + (size_t)B_*Q_*H_;          //  524288 f
    float* s_prt = kh4   + (size_t)B_*H_*K_;          //    8192 f
    float* o_prt = s_prt + (size_t)B_*Q_*8;           // 4194304 f (16 MB)
    float* psum  = o_prt + (size_t)8*B_*Q_*DV_;       // 5242880 f (21 MB)

    proj_part      <<<dim3(320),  dim3(256), 0, stream>>>(q, k, wq, wk, vl, psum);
    proj_reduce    <<<dim3(640),  dim3(256), 0, stream>>>(psum, vl, qh_s, (float4*)kh4);
    attn_part      <<<dim3(1024), dim3(256), 0, stream>>>(qh_s, (const float4*)kh4, wv, vl, v, s_prt, (float4*)o_prt);
    finalize_kernel<<<dim3(512),  dim3(256), 0, stream>>>((const float4*)o_prt, s_prt, vl, (float4*)out);
}